// Round 8
// baseline (978.935 us; speedup 1.0000x reference)
//
#include <hip/hip_runtime.h>
#include <stdint.h>

#define NN 50000
#define RR 64
#define EE 20000
#define NB 16            // bases
#define IND 256
#define OUTD 256
#define KK 4352          // 16*256 (V) + 256 (x for root)
#define NE (RR * EE)     // 1,280,000 edges
#define CHUNK 12800      // dst rows per V chunk (4 chunks)
#define NCHUNK 4
#define GITER 68         // KK / 64

typedef __attribute__((ext_vector_type(8))) short bf16x8;
typedef __attribute__((ext_vector_type(4))) float f32x4;

__device__ __forceinline__ unsigned short f2bf(float f) {
  union { float f; unsigned u; } v; v.f = f;
  unsigned r = v.u + 0x7FFFu + ((v.u >> 16) & 1u);   // RNE
  return (unsigned short)(r >> 16);
}
__device__ __forceinline__ float bf2f(unsigned short s) {
  union { unsigned u; float f; } v; v.u = ((unsigned)s) << 16;
  return v.f;
}

// ---------- x -> bf16 ----------
__global__ __launch_bounds__(256) void k_xbf(const float* __restrict__ x,
                                             unsigned short* __restrict__ xb) {
  const size_t g = (size_t)(blockIdx.x * 256 + threadIdx.x) * 8;
  float4 v0 = *reinterpret_cast<const float4*>(x + g);
  float4 v1 = *reinterpret_cast<const float4*>(x + g + 4);
  ushort4 o0 = {f2bf(v0.x), f2bf(v0.y), f2bf(v0.z), f2bf(v0.w)};
  ushort4 o1 = {f2bf(v1.x), f2bf(v1.y), f2bf(v1.z), f2bf(v1.w)};
  *reinterpret_cast<ushort4*>(xb + g) = o0;
  *reinterpret_cast<ushort4*>(xb + g + 4) = o1;
}

// ---------- counting sort of edges by dst ----------
__global__ __launch_bounds__(256) void k_hist(const int* __restrict__ edst,
                                              int* __restrict__ cnt) {
  const int g = blockIdx.x * 256 + threadIdx.x;
  atomicAdd(&cnt[edst[g]], 1);
}

__global__ __launch_bounds__(1024) void k_scan(const int* __restrict__ cnt,
                                               int* __restrict__ rowptr,
                                               int* __restrict__ wof) {
  __shared__ int ps[1024];
  const int t = threadIdx.x;
  const int base = t * 49;                           // 49*1024 >= NN
  int sum = 0;
  for (int j = 0; j < 49; ++j) { const int idx = base + j; if (idx < NN) sum += cnt[idx]; }
  ps[t] = sum; __syncthreads();
  for (int off = 1; off < 1024; off <<= 1) {
    int v = (t >= off) ? ps[t - off] : 0;
    __syncthreads();
    ps[t] += v;
    __syncthreads();
  }
  int run = ps[t] - sum;
  for (int j = 0; j < 49; ++j) {
    const int idx = base + j;
    if (idx < NN) { rowptr[idx] = run; wof[idx] = run; run += cnt[idx]; }
  }
  if (t == 1023) rowptr[NN] = ps[1023];
}

__global__ __launch_bounds__(256) void k_scatter(const int* __restrict__ esrc,
                                                 const int* __restrict__ edst,
                                                 int* __restrict__ wof,
                                                 unsigned* __restrict__ payload) {
  const int g = blockIdx.x * 256 + threadIdx.x;
  const int d = edst[g];
  const int src = esrc[g];
  const int r = g / EE;
  const int pos = atomicAdd(&wof[d], 1);
  payload[pos] = ((unsigned)r << 18) | (unsigned)src;
}

// ---------- bt[o][k] bf16: k<4096 -> basis[k][o] flat; else root[k-4096][o] ----------
__global__ __launch_bounds__(256) void k_bt(const float* __restrict__ basis,
                                            const float* __restrict__ root,
                                            unsigned short* __restrict__ bt) {
  const int o = blockIdx.x;
  for (int k = threadIdx.x; k < KK; k += 256) {
    float v;
    if (k < 4096) v = basis[(size_t)k * 256 + o];
    else          v = root[(size_t)(k - 4096) * 256 + o];
    bt[(size_t)o * KK + k] = f2bf(v);
  }
}

// ---------- V-build: one wave per dst; V[n,b,i] = (1/deg) * sum_e att[r_e,b]*x[src_e,i] ----------
__global__ __launch_bounds__(256) void k_vbuild(
    const unsigned short* __restrict__ xbf, const float* __restrict__ att,
    const float* __restrict__ deg, const int* __restrict__ rowptr,
    const unsigned* __restrict__ payload, unsigned short* __restrict__ Vb,
    const int c0) {
  __shared__ float attl[RR * NB];                    // 4 KB
  const int t = threadIdx.x;
  *reinterpret_cast<float4*>(&attl[t * 4]) =
      *reinterpret_cast<const float4*>(&att[t * 4]); // 1024 floats, 4/thread
  __syncthreads();
  const int lane = t & 63;
  const int n = c0 + blockIdx.x * 4 + (t >> 6);
  if (n >= NN) return;
  const int k0 = rowptr[n], k1 = rowptr[n + 1];
  float acc[NB][4];
#pragma unroll
  for (int b = 0; b < NB; ++b)
#pragma unroll
    for (int q = 0; q < 4; ++q) acc[b][q] = 0.f;

  unsigned pkA = 0, pkB = 0;
  ushort4 xvA = {0, 0, 0, 0}, xvB = {0, 0, 0, 0};
  if (k0 < k1) {
    pkA = payload[k0];
    xvA = *reinterpret_cast<const ushort4*>(xbf + (size_t)(pkA & 0x3FFFFu) * IND + lane * 4);
  }
  if (k0 + 1 < k1) {
    pkB = payload[k0 + 1];
    xvB = *reinterpret_cast<const ushort4*>(xbf + (size_t)(pkB & 0x3FFFFu) * IND + lane * 4);
  }
  for (int k = k0; k < k1; ++k) {
    unsigned pkC = 0; ushort4 xvC = {0, 0, 0, 0};
    if (k + 2 < k1) {                                // depth-2 prefetch
      pkC = payload[k + 2];
      xvC = *reinterpret_cast<const ushort4*>(xbf + (size_t)(pkC & 0x3FFFFu) * IND + lane * 4);
    }
    const int r = (int)(pkA >> 18);
    const float fx0 = bf2f(xvA.x), fx1 = bf2f(xvA.y), fx2 = bf2f(xvA.z), fx3 = bf2f(xvA.w);
#pragma unroll
    for (int b4 = 0; b4 < 4; ++b4) {
      const float4 a4 = *reinterpret_cast<const float4*>(&attl[r * NB + b4 * 4]);
      const float aa[4] = {a4.x, a4.y, a4.z, a4.w};
#pragma unroll
      for (int q = 0; q < 4; ++q) {
        float* ac = acc[b4 * 4 + q];
        ac[0] = fmaf(aa[q], fx0, ac[0]);
        ac[1] = fmaf(aa[q], fx1, ac[1]);
        ac[2] = fmaf(aa[q], fx2, ac[2]);
        ac[3] = fmaf(aa[q], fx3, ac[3]);
      }
    }
    pkA = pkB; xvA = xvB; pkB = pkC; xvB = xvC;
  }
  const float iv = 1.0f / deg[n];
  unsigned short* vr = Vb + (size_t)(n - c0) * 4096 + lane * 4;
#pragma unroll
  for (int b = 0; b < NB; ++b) {
    ushort4 s;
    s.x = f2bf(acc[b][0] * iv); s.y = f2bf(acc[b][1] * iv);
    s.z = f2bf(acc[b][2] * iv); s.w = f2bf(acc[b][3] * iv);
    *reinterpret_cast<ushort4*>(vr + (size_t)b * 256) = s;
  }
}

// ---------- GEMM: out = [V/deg | x] @ bt^T, 64x128 tile, 2 waves, dbuf LDS ----------
__global__ __launch_bounds__(128) void k_gemm2(
    const unsigned short* __restrict__ Vb, const unsigned short* __restrict__ xbf,
    const unsigned short* __restrict__ bt, float* __restrict__ out, const int c0) {
  __shared__ unsigned short As[2][64 * 64];          // 8 KB each
  __shared__ unsigned short Bs[2][128 * 64];         // 16 KB each
  const int t = threadIdx.x;
  const int rb = blockIdx.x, cb = blockIdx.y;
  const int lane = t & 63, w = t >> 6;
  const int lc = lane & 15, lg = lane >> 4;

  const int arow = t >> 1, ah = t & 1;               // A staging: 2 thr/row
  const int growl = rb * 64 + arow;                  // chunk-local row
  const int grow = c0 + growl;
  const bool okA = grow < NN;
  const unsigned short* btc = bt + (size_t)(cb * 128 + t) * KK;   // B staging: 1 thr/col

  bf16x8 ra[4], rbv[8];
  bf16x8 zv;
#pragma unroll
  for (int q = 0; q < 8; ++q) zv[q] = 0;

#define STAGE(IT)                                                                  \
  {                                                                                \
    const int it_ = (IT);                                                          \
    if (okA) {                                                                     \
      const unsigned short* asrc = (it_ < 64)                                      \
          ? Vb + (size_t)growl * 4096 + it_ * 64 + ah * 32                         \
          : xbf + (size_t)grow * 256 + (it_ - 64) * 64 + ah * 32;                  \
      _Pragma("unroll")                                                            \
      for (int j = 0; j < 4; ++j) ra[j] = *reinterpret_cast<const bf16x8*>(asrc + j * 8); \
    } else {                                                                       \
      _Pragma("unroll")                                                            \
      for (int j = 0; j < 4; ++j) ra[j] = zv;                                      \
    }                                                                              \
    const unsigned short* bsrc = btc + it_ * 64;                                   \
    _Pragma("unroll")                                                              \
    for (int j = 0; j < 8; ++j) rbv[j] = *reinterpret_cast<const bf16x8*>(bsrc + j * 8); \
  }

#define COMMIT(BUF)                                                                \
  {                                                                                \
    const int b_ = (BUF);                                                          \
    _Pragma("unroll")                                                              \
    for (int j = 0; j < 4; ++j) {                                                  \
      const int ch = ah * 4 + j;                                                   \
      *reinterpret_cast<bf16x8*>(&As[b_][arow * 64 + ((ch ^ (arow & 7)) * 8)]) = ra[j]; \
    }                                                                              \
    _Pragma("unroll")                                                              \
    for (int j = 0; j < 8; ++j)                                                    \
      *reinterpret_cast<bf16x8*>(&Bs[b_][t * 64 + ((j ^ (t & 7)) * 8)]) = rbv[j];  \
  }

  f32x4 acc[4][4];
  const f32x4 zf = {0.f, 0.f, 0.f, 0.f};
#pragma unroll
  for (int m = 0; m < 4; ++m)
#pragma unroll
    for (int n = 0; n < 4; ++n) acc[m][n] = zf;

  STAGE(0); COMMIT(0);
  int cur = 0;
  for (int it = 0; it < GITER; ++it) {
    __syncthreads();                                 // buf[cur] ready for all
    if (it + 1 < GITER) STAGE(it + 1);               // loads overlap MFMA below
#pragma unroll
    for (int kk = 0; kk < 2; ++kk) {
      bf16x8 af[4], bfm[4];
      const int ch = kk * 4 + lg;
#pragma unroll
      for (int m = 0; m < 4; ++m) {
        const int r2 = m * 16 + lc;
        af[m] = *reinterpret_cast<const bf16x8*>(&As[cur][r2 * 64 + ((ch ^ (r2 & 7)) * 8)]);
      }
#pragma unroll
      for (int n = 0; n < 4; ++n) {
        const int c2 = w * 64 + n * 16 + lc;
        bfm[n] = *reinterpret_cast<const bf16x8*>(&Bs[cur][c2 * 64 + ((ch ^ (c2 & 7)) * 8)]);
      }
#pragma unroll
      for (int m = 0; m < 4; ++m)
#pragma unroll
        for (int n = 0; n < 4; ++n)
          acc[m][n] = __builtin_amdgcn_mfma_f32_16x16x32_bf16(af[m], bfm[n], acc[m][n], 0, 0, 0);
    }
    if (it + 1 < GITER) { COMMIT(cur ^ 1); cur ^= 1; }
  }
#pragma unroll
  for (int m = 0; m < 4; ++m) {
#pragma unroll
    for (int j = 0; j < 4; ++j) {
      const int n = c0 + rb * 64 + m * 16 + lg * 4 + j;
      if (n < NN) {
        float* orow = out + (size_t)n * OUTD + cb * 128 + w * 64 + lc;
        orow[0]  = acc[m][0][j];
        orow[16] = acc[m][1][j];
        orow[32] = acc[m][2][j];
        orow[48] = acc[m][3][j];
      }
    }
  }
}

extern "C" void kernel_launch(void* const* d_in, const int* in_sizes, int n_in,
                              void* d_out, int out_size, void* d_ws, size_t ws_size,
                              hipStream_t stream) {
  (void)in_sizes; (void)n_in; (void)out_size; (void)ws_size;
  const float* x     = (const float*)d_in[0];
  const float* att   = (const float*)d_in[1];
  const float* basis = (const float*)d_in[2];
  const float* root  = (const float*)d_in[3];
  const float* deg   = (const float*)d_in[4];
  const int*   esrc  = (const int*)d_in[5];
  const int*   edst  = (const int*)d_in[6];
  float* out = (float*)d_out;

  char* p = (char*)d_ws;
  unsigned short* Vb  = (unsigned short*)p; p += (size_t)CHUNK * 4096 * 2;  // 104.9 MB
  unsigned short* xbf = (unsigned short*)p; p += (size_t)NN * IND * 2;      // 25.6 MB
  unsigned short* bt  = (unsigned short*)p; p += (size_t)OUTD * KK * 2;     // 2.2 MB
  unsigned* payload   = (unsigned*)p;       p += (size_t)NE * 4;            // 5.1 MB
  int* rowptr         = (int*)p;            p += (size_t)(NN + 1) * 4;
  int* wof            = (int*)p;            p += (size_t)NN * 4;
  int* cnt            = (int*)p;            p += (size_t)NN * 4;

  hipMemsetAsync(cnt, 0, (size_t)NN * 4, stream);
  hipLaunchKernelGGL(k_xbf,     dim3(NN * IND / 2048), dim3(256),  0, stream, x, xbf);
  hipLaunchKernelGGL(k_hist,    dim3(NE / 256),        dim3(256),  0, stream, edst, cnt);
  hipLaunchKernelGGL(k_scan,    dim3(1),               dim3(1024), 0, stream, cnt, rowptr, wof);
  hipLaunchKernelGGL(k_scatter, dim3(NE / 256),        dim3(256),  0, stream, esrc, edst, wof, payload);
  hipLaunchKernelGGL(k_bt,      dim3(OUTD),            dim3(256),  0, stream, basis, root, bt);

  for (int c = 0; c < NCHUNK; ++c) {
    const int c0 = c * CHUNK;
    hipLaunchKernelGGL(k_vbuild, dim3(CHUNK / 4), dim3(256), 0, stream,
                       xbf, att, deg, rowptr, payload, Vb, c0);
    hipLaunchKernelGGL(k_gemm2, dim3(CHUNK / 64, 2), dim3(128), 0, stream,
                       Vb, xbf, bt, out, c0);
  }
}

// Round 9
// 674.864 us; speedup vs baseline: 1.4506x; 1.4506x over previous
//
#include <hip/hip_runtime.h>
#include <stdint.h>

#define NN 50000
#define RR 64
#define EE 20000
#define NB 16            // bases
#define IND 256
#define OUTD 256
#define KK 4352          // 16*256 (V) + 256 (x for root)
#define NE (RR * EE)     // 1,280,000 edges
#define GITER 68         // KK / 64
#define SCANB 49         // ceil(NN/1024)

typedef __attribute__((ext_vector_type(8))) short bf16x8;
typedef __attribute__((ext_vector_type(4))) float f32x4;

__device__ __forceinline__ unsigned short f2bf(float f) {
  union { float f; unsigned u; } v; v.f = f;
  unsigned r = v.u + 0x7FFFu + ((v.u >> 16) & 1u);   // RNE
  return (unsigned short)(r >> 16);
}
__device__ __forceinline__ float bf2f(unsigned short s) {
  union { unsigned u; float f; } v; v.u = ((unsigned)s) << 16;
  return v.f;
}

// ---------- x -> bf16 ----------
__global__ __launch_bounds__(256) void k_xbf(const float* __restrict__ x,
                                             unsigned short* __restrict__ xb) {
  const size_t g = (size_t)(blockIdx.x * 256 + threadIdx.x) * 8;
  float4 v0 = *reinterpret_cast<const float4*>(x + g);
  float4 v1 = *reinterpret_cast<const float4*>(x + g + 4);
  ushort4 o0 = {f2bf(v0.x), f2bf(v0.y), f2bf(v0.z), f2bf(v0.w)};
  ushort4 o1 = {f2bf(v1.x), f2bf(v1.y), f2bf(v1.z), f2bf(v1.w)};
  *reinterpret_cast<ushort4*>(xb + g) = o0;
  *reinterpret_cast<ushort4*>(xb + g + 4) = o1;
}

// ---------- counting sort of edges by dst ----------
__global__ __launch_bounds__(256) void k_hist(const int* __restrict__ edst,
                                              int* __restrict__ cnt) {
  const int g = blockIdx.x * 256 + threadIdx.x;
  atomicAdd(&cnt[edst[g]], 1);
}

// block-local scan: 49 blocks x 1024 elems (4/thread)
__global__ __launch_bounds__(256) void k_scan_a(const int* __restrict__ cnt,
                                                int* __restrict__ rowptr,
                                                int* __restrict__ bsum) {
  __shared__ int ps[256];
  const int t = threadIdx.x, blk = blockIdx.x;
  const int base = blk * 1024 + t * 4;
  int v[4];
#pragma unroll
  for (int q = 0; q < 4; ++q) {
    const int idx = base + q;
    v[q] = (idx < NN) ? cnt[idx] : 0;
  }
  const int s = v[0] + v[1] + v[2] + v[3];
  ps[t] = s;
  __syncthreads();
  for (int off = 1; off < 256; off <<= 1) {
    const int u = (t >= off) ? ps[t - off] : 0;
    __syncthreads();
    ps[t] += u;
    __syncthreads();
  }
  int run = ps[t] - s;                               // exclusive prefix
#pragma unroll
  for (int q = 0; q < 4; ++q) {
    const int idx = base + q;
    if (idx < NN) rowptr[idx] = run;
    run += v[q];
  }
  if (t == 255) bsum[blk] = ps[255];
}

// scan the 49 block sums (single wave)
__global__ __launch_bounds__(64) void k_scan_b(const int* __restrict__ bsum,
                                               int* __restrict__ boff,
                                               int* __restrict__ rowptr) {
  const int t = threadIdx.x;
  const int own = (t < SCANB) ? bsum[t] : 0;
  int v = own;
  for (int off = 1; off < 64; off <<= 1) {
    const int u = __shfl_up(v, off);
    if (t >= off) v += u;
  }
  if (t < SCANB) boff[t] = v - own;                  // exclusive
  if (t == SCANB - 1) rowptr[NN] = v;                // total == NE
}

// add block offsets; mirror into wof
__global__ __launch_bounds__(256) void k_scan_c(const int* __restrict__ boff,
                                                int* __restrict__ rowptr,
                                                int* __restrict__ wof) {
  const int t = threadIdx.x, blk = blockIdx.x;
  const int base = blk * 1024 + t * 4;
  const int bo = boff[blk];
#pragma unroll
  for (int q = 0; q < 4; ++q) {
    const int idx = base + q;
    if (idx < NN) {
      const int val = rowptr[idx] + bo;
      rowptr[idx] = val;
      wof[idx] = val;
    }
  }
}

__global__ __launch_bounds__(256) void k_scatter(const int* __restrict__ esrc,
                                                 const int* __restrict__ edst,
                                                 int* __restrict__ wof,
                                                 unsigned* __restrict__ payload) {
  const int g = blockIdx.x * 256 + threadIdx.x;
  const int d = edst[g];
  const int src = esrc[g];
  const int r = g / EE;
  const int pos = atomicAdd(&wof[d], 1);
  payload[pos] = ((unsigned)r << 18) | (unsigned)src;
}

// ---------- bt[o][k] bf16: k<4096 -> basis[k][o] flat; else root[k-4096][o] ----------
__global__ __launch_bounds__(256) void k_bt(const float* __restrict__ basis,
                                            const float* __restrict__ root,
                                            unsigned short* __restrict__ bt) {
  const int o = blockIdx.x;
  for (int k = threadIdx.x; k < KK; k += 256) {
    float v;
    if (k < 4096) v = basis[(size_t)k * 256 + o];
    else          v = root[(size_t)(k - 4096) * 256 + o];
    bt[(size_t)o * KK + k] = f2bf(v);
  }
}

// ---------- V-build: one wave per dst; V[n,b,i] = (1/deg) * sum_e att[r_e,b]*x[src_e,i] ----------
__global__ __launch_bounds__(256) void k_vbuild(
    const unsigned short* __restrict__ xbf, const float* __restrict__ att,
    const float* __restrict__ deg, const int* __restrict__ rowptr,
    const unsigned* __restrict__ payload, unsigned short* __restrict__ Vb,
    const int c0) {
  __shared__ float attl[RR * NB];                    // 4 KB
  const int t = threadIdx.x;
  *reinterpret_cast<float4*>(&attl[t * 4]) =
      *reinterpret_cast<const float4*>(&att[t * 4]);
  __syncthreads();
  const int lane = t & 63;
  const int n = c0 + blockIdx.x * 4 + (t >> 6);
  if (n >= NN) return;
  const int k0 = rowptr[n], k1 = rowptr[n + 1];
  float acc[NB][4];
#pragma unroll
  for (int b = 0; b < NB; ++b)
#pragma unroll
    for (int q = 0; q < 4; ++q) acc[b][q] = 0.f;

  unsigned pkA = 0, pkB = 0;
  ushort4 xvA = {0, 0, 0, 0}, xvB = {0, 0, 0, 0};
  if (k0 < k1) {
    pkA = payload[k0];
    xvA = *reinterpret_cast<const ushort4*>(xbf + (size_t)(pkA & 0x3FFFFu) * IND + lane * 4);
  }
  if (k0 + 1 < k1) {
    pkB = payload[k0 + 1];
    xvB = *reinterpret_cast<const ushort4*>(xbf + (size_t)(pkB & 0x3FFFFu) * IND + lane * 4);
  }
  for (int k = k0; k < k1; ++k) {
    unsigned pkC = 0; ushort4 xvC = {0, 0, 0, 0};
    if (k + 2 < k1) {
      pkC = payload[k + 2];
      xvC = *reinterpret_cast<const ushort4*>(xbf + (size_t)(pkC & 0x3FFFFu) * IND + lane * 4);
    }
    const int r = (int)(pkA >> 18);
    const float fx0 = bf2f(xvA.x), fx1 = bf2f(xvA.y), fx2 = bf2f(xvA.z), fx3 = bf2f(xvA.w);
#pragma unroll
    for (int b4 = 0; b4 < 4; ++b4) {
      const float4 a4 = *reinterpret_cast<const float4*>(&attl[r * NB + b4 * 4]);
      const float aa[4] = {a4.x, a4.y, a4.z, a4.w};
#pragma unroll
      for (int q = 0; q < 4; ++q) {
        float* ac = acc[b4 * 4 + q];
        ac[0] = fmaf(aa[q], fx0, ac[0]);
        ac[1] = fmaf(aa[q], fx1, ac[1]);
        ac[2] = fmaf(aa[q], fx2, ac[2]);
        ac[3] = fmaf(aa[q], fx3, ac[3]);
      }
    }
    pkA = pkB; xvA = xvB; pkB = pkC; xvB = xvC;
  }
  const float iv = 1.0f / deg[n];
  unsigned short* vr = Vb + (size_t)(n - c0) * 4096 + lane * 4;
#pragma unroll
  for (int b = 0; b < NB; ++b) {
    ushort4 s;
    s.x = f2bf(acc[b][0] * iv); s.y = f2bf(acc[b][1] * iv);
    s.z = f2bf(acc[b][2] * iv); s.w = f2bf(acc[b][3] * iv);
    *reinterpret_cast<ushort4*>(vr + (size_t)b * 256) = s;
  }
}

// ---------- GEMM: out = [V/deg | x] @ bt^T, 128x128 tile, 4 waves (2x2 of 64x64), dbuf ----------
__global__ __launch_bounds__(256) void k_gemm3(
    const unsigned short* __restrict__ Vb, const unsigned short* __restrict__ xbf,
    const unsigned short* __restrict__ bt, float* __restrict__ out, const int c0) {
  __shared__ unsigned short As[2][128 * 64];         // 16 KB each
  __shared__ unsigned short Bs[2][128 * 64];         // 16 KB each
  const int t = threadIdx.x;
  const int rb = blockIdx.x, cb = blockIdx.y;
  const int lane = t & 63, w = t >> 6;
  const int wr = w >> 1, wc = w & 1;                 // 2x2 waves of 64x64
  const int lc = lane & 15, lg = lane >> 4;

  const int arow = t >> 1, ah = t & 1;               // A staging: 2 thr/row, 32 k each
  const int growl = rb * 128 + arow;                 // chunk-local row
  const int grow = c0 + growl;
  const bool okA = grow < NN;
  const int bcol = t >> 1, bh = t & 1;               // B staging: 2 thr/col
  const unsigned short* btc = bt + (size_t)(cb * 128 + bcol) * KK + bh * 32;

  bf16x8 ra[4], rbv[4];
  bf16x8 zv;
#pragma unroll
  for (int q = 0; q < 8; ++q) zv[q] = 0;

#define STAGE(IT)                                                                  \
  {                                                                                \
    const int it_ = (IT);                                                          \
    if (okA) {                                                                     \
      const unsigned short* asrc = (it_ < 64)                                      \
          ? Vb + (size_t)growl * 4096 + it_ * 64 + ah * 32                         \
          : xbf + (size_t)grow * 256 + (it_ - 64) * 64 + ah * 32;                  \
      _Pragma("unroll")                                                            \
      for (int j = 0; j < 4; ++j) ra[j] = *reinterpret_cast<const bf16x8*>(asrc + j * 8); \
    } else {                                                                       \
      _Pragma("unroll")                                                            \
      for (int j = 0; j < 4; ++j) ra[j] = zv;                                      \
    }                                                                              \
    const unsigned short* bsrc = btc + it_ * 64;                                   \
    _Pragma("unroll")                                                              \
    for (int j = 0; j < 4; ++j) rbv[j] = *reinterpret_cast<const bf16x8*>(bsrc + j * 8); \
  }

#define COMMIT(BUF)                                                                \
  {                                                                                \
    const int b_ = (BUF);                                                          \
    _Pragma("unroll")                                                              \
    for (int j = 0; j < 4; ++j) {                                                  \
      const int ch = ah * 4 + j;                                                   \
      *reinterpret_cast<bf16x8*>(&As[b_][arow * 64 + ((ch ^ (arow & 7)) * 8)]) = ra[j]; \
    }                                                                              \
    _Pragma("unroll")                                                              \
    for (int j = 0; j < 4; ++j) {                                                  \
      const int ch = bh * 4 + j;                                                   \
      *reinterpret_cast<bf16x8*>(&Bs[b_][bcol * 64 + ((ch ^ (bcol & 7)) * 8)]) = rbv[j]; \
    }                                                                              \
  }

  f32x4 acc[4][4];
  const f32x4 zf = {0.f, 0.f, 0.f, 0.f};
#pragma unroll
  for (int m = 0; m < 4; ++m)
#pragma unroll
    for (int n = 0; n < 4; ++n) acc[m][n] = zf;

  STAGE(0); COMMIT(0);
  int cur = 0;
  for (int it = 0; it < GITER; ++it) {
    __syncthreads();                                 // buf[cur] committed by all
    if (it + 1 < GITER) STAGE(it + 1);               // global loads overlap MFMA
#pragma unroll
    for (int kk = 0; kk < 2; ++kk) {
      bf16x8 af[4], bfm[4];
      const int ch = kk * 4 + lg;
#pragma unroll
      for (int m = 0; m < 4; ++m) {
        const int r2 = wr * 64 + m * 16 + lc;
        af[m] = *reinterpret_cast<const bf16x8*>(&As[cur][r2 * 64 + ((ch ^ (r2 & 7)) * 8)]);
      }
#pragma unroll
      for (int n = 0; n < 4; ++n) {
        const int c2 = wc * 64 + n * 16 + lc;
        bfm[n] = *reinterpret_cast<const bf16x8*>(&Bs[cur][c2 * 64 + ((ch ^ (c2 & 7)) * 8)]);
      }
#pragma unroll
      for (int m = 0; m < 4; ++m)
#pragma unroll
        for (int n = 0; n < 4; ++n)
          acc[m][n] = __builtin_amdgcn_mfma_f32_16x16x32_bf16(af[m], bfm[n], acc[m][n], 0, 0, 0);
    }
    if (it + 1 < GITER) { COMMIT(cur ^ 1); cur ^= 1; }
  }
#pragma unroll
  for (int m = 0; m < 4; ++m) {
#pragma unroll
    for (int j = 0; j < 4; ++j) {
      const int n = c0 + rb * 128 + wr * 64 + m * 16 + lg * 4 + j;
      if (n < NN) {
        float* orow = out + (size_t)n * OUTD + cb * 128 + wc * 64 + lc;
        orow[0]  = acc[m][0][j];
        orow[16] = acc[m][1][j];
        orow[32] = acc[m][2][j];
        orow[48] = acc[m][3][j];
      }
    }
  }
}

extern "C" void kernel_launch(void* const* d_in, const int* in_sizes, int n_in,
                              void* d_out, int out_size, void* d_ws, size_t ws_size,
                              hipStream_t stream) {
  (void)in_sizes; (void)n_in; (void)out_size;
  const float* x     = (const float*)d_in[0];
  const float* att   = (const float*)d_in[1];
  const float* basis = (const float*)d_in[2];
  const float* root  = (const float*)d_in[3];
  const float* deg   = (const float*)d_in[4];
  const int*   esrc  = (const int*)d_in[5];
  const int*   edst  = (const int*)d_in[6];
  float* out = (float*)d_out;

  char* p = (char*)d_ws;
  unsigned short* xbf = (unsigned short*)p; p += (size_t)NN * IND * 2;      // 25.6 MB
  unsigned short* bt  = (unsigned short*)p; p += (size_t)OUTD * KK * 2;     // 2.2 MB
  unsigned* payload   = (unsigned*)p;       p += (size_t)NE * 4;            // 5.1 MB
  int* rowptr         = (int*)p;            p += (size_t)(NN + 1) * 4;
  int* wof            = (int*)p;            p += (size_t)NN * 4;
  int* cnt            = (int*)p;            p += (size_t)NN * 4;
  int* bsum           = (int*)p;            p += 64 * 4;
  int* boff           = (int*)p;            p += 64 * 4;
  uintptr_t up = ((uintptr_t)p + 255) & ~(uintptr_t)255;
  unsigned short* Vb  = (unsigned short*)up;
  const size_t used = (size_t)((char*)Vb - (char*)d_ws);

  int chunk = 25600;                                  // prefer 2 chunks (210 MB V)
  if (ws_size - used < (size_t)chunk * 4096 * 2) chunk = 12800;

  hipMemsetAsync(cnt, 0, (size_t)NN * 4, stream);
  hipLaunchKernelGGL(k_xbf,     dim3(NN * IND / 2048), dim3(256),  0, stream, x, xbf);
  hipLaunchKernelGGL(k_hist,    dim3(NE / 256),        dim3(256),  0, stream, edst, cnt);
  hipLaunchKernelGGL(k_scan_a,  dim3(SCANB),           dim3(256),  0, stream, cnt, rowptr, bsum);
  hipLaunchKernelGGL(k_scan_b,  dim3(1),               dim3(64),   0, stream, bsum, boff, rowptr);
  hipLaunchKernelGGL(k_scan_c,  dim3(SCANB),           dim3(256),  0, stream, boff, rowptr, wof);
  hipLaunchKernelGGL(k_scatter, dim3(NE / 256),        dim3(256),  0, stream, esrc, edst, wof, payload);
  hipLaunchKernelGGL(k_bt,      dim3(OUTD),            dim3(256),  0, stream, basis, root, bt);

  for (int c0 = 0; c0 < NN; c0 += chunk) {
    const int rows = (NN - c0 < chunk) ? (NN - c0) : chunk;
    hipLaunchKernelGGL(k_vbuild, dim3((rows + 3) / 4), dim3(256), 0, stream,
                       xbf, att, deg, rowptr, payload, Vb, c0);
    hipLaunchKernelGGL(k_gemm3, dim3((rows + 127) / 128, 2), dim3(256), 0, stream,
                       Vb, xbf, bt, out, c0);
  }
}

// Round 10
// 653.473 us; speedup vs baseline: 1.4981x; 1.0327x over previous
//
#include <hip/hip_runtime.h>
#include <stdint.h>

#define NN 50000
#define RR 64
#define EE 20000
#define NB 16            // bases
#define IND 256
#define OUTD 256
#define KK 4352          // 16*256 (V) + 256 (x for root)
#define NE (RR * EE)     // 1,280,000 edges
#define GITER 68         // KK / 64
#define SCANB 49         // ceil(NN/1024)

typedef __attribute__((ext_vector_type(8))) short bf16x8;
typedef __attribute__((ext_vector_type(4))) float f32x4;
typedef __attribute__((ext_vector_type(2))) float f32x2;

__device__ __forceinline__ unsigned short f2bf(float f) {
  union { float f; unsigned u; } v; v.f = f;
  unsigned r = v.u + 0x7FFFu + ((v.u >> 16) & 1u);   // RNE
  return (unsigned short)(r >> 16);
}
__device__ __forceinline__ float asf(unsigned u) {
  union { unsigned u; float f; } v; v.u = u; return v.f;
}

// ---------- x -> bf16, chunk-swizzled: chunk ch of row r stored at ch^(r&7) ----------
__global__ __launch_bounds__(256) void k_xbf(const float* __restrict__ x,
                                             unsigned short* __restrict__ xb) {
  const int gt = blockIdx.x * 256 + threadIdx.x;     // one 8-elem chunk per thread
  const size_t g = (size_t)gt * 8;
  const int row = gt >> 5;                           // g / 256
  const int k = (gt & 31) * 8;                       // g % 256
  float4 v0 = *reinterpret_cast<const float4*>(x + g);
  float4 v1 = *reinterpret_cast<const float4*>(x + g + 4);
  union { bf16x8 v; unsigned short u[8]; } pk;
  pk.u[0]=f2bf(v0.x); pk.u[1]=f2bf(v0.y); pk.u[2]=f2bf(v0.z); pk.u[3]=f2bf(v0.w);
  pk.u[4]=f2bf(v1.x); pk.u[5]=f2bf(v1.y); pk.u[6]=f2bf(v1.z); pk.u[7]=f2bf(v1.w);
  const int tile = k >> 6, ch = (k >> 3) & 7;
  *reinterpret_cast<bf16x8*>(
      xb + (size_t)row * 256 + tile * 64 + ((ch ^ (row & 7)) << 3)) = pk.v;
}

// ---------- counting sort of edges by dst ----------
__global__ __launch_bounds__(256) void k_hist(const int* __restrict__ edst,
                                              int* __restrict__ cnt) {
  const int g = blockIdx.x * 256 + threadIdx.x;
  atomicAdd(&cnt[edst[g]], 1);
}

__global__ __launch_bounds__(256) void k_scan_a(const int* __restrict__ cnt,
                                                int* __restrict__ rowptr,
                                                int* __restrict__ bsum) {
  __shared__ int ps[256];
  const int t = threadIdx.x, blk = blockIdx.x;
  const int base = blk * 1024 + t * 4;
  int v[4];
#pragma unroll
  for (int q = 0; q < 4; ++q) {
    const int idx = base + q;
    v[q] = (idx < NN) ? cnt[idx] : 0;
  }
  const int s = v[0] + v[1] + v[2] + v[3];
  ps[t] = s;
  __syncthreads();
  for (int off = 1; off < 256; off <<= 1) {
    const int u = (t >= off) ? ps[t - off] : 0;
    __syncthreads();
    ps[t] += u;
    __syncthreads();
  }
  int run = ps[t] - s;
#pragma unroll
  for (int q = 0; q < 4; ++q) {
    const int idx = base + q;
    if (idx < NN) rowptr[idx] = run;
    run += v[q];
  }
  if (t == 255) bsum[blk] = ps[255];
}

__global__ __launch_bounds__(64) void k_scan_b(const int* __restrict__ bsum,
                                               int* __restrict__ boff,
                                               int* __restrict__ rowptr) {
  const int t = threadIdx.x;
  const int own = (t < SCANB) ? bsum[t] : 0;
  int v = own;
  for (int off = 1; off < 64; off <<= 1) {
    const int u = __shfl_up(v, off);
    if (t >= off) v += u;
  }
  if (t < SCANB) boff[t] = v - own;
  if (t == SCANB - 1) rowptr[NN] = v;
}

__global__ __launch_bounds__(256) void k_scan_c(const int* __restrict__ boff,
                                                int* __restrict__ rowptr,
                                                int* __restrict__ wof) {
  const int t = threadIdx.x, blk = blockIdx.x;
  const int base = blk * 1024 + t * 4;
  const int bo = boff[blk];
#pragma unroll
  for (int q = 0; q < 4; ++q) {
    const int idx = base + q;
    if (idx < NN) {
      const int val = rowptr[idx] + bo;
      rowptr[idx] = val;
      wof[idx] = val;
    }
  }
}

__global__ __launch_bounds__(256) void k_scatter(const int* __restrict__ esrc,
                                                 const int* __restrict__ edst,
                                                 int* __restrict__ wof,
                                                 unsigned* __restrict__ payload) {
  const int g = blockIdx.x * 256 + threadIdx.x;
  const int d = edst[g];
  const int src = esrc[g];
  const int r = g / EE;
  const int pos = atomicAdd(&wof[d], 1);
  payload[pos] = ((unsigned)r << 18) | (unsigned)src;
}

// ---------- bt[o][k] bf16, chunk-swizzled by (o&7) ----------
__global__ __launch_bounds__(256) void k_bt(const float* __restrict__ basis,
                                            const float* __restrict__ root,
                                            unsigned short* __restrict__ bt) {
  const int o = blockIdx.x;
  for (int k = threadIdx.x; k < KK; k += 256) {
    float v;
    if (k < 4096) v = basis[(size_t)k * 256 + o];
    else          v = root[(size_t)(k - 4096) * 256 + o];
    const int tile = k >> 6, ch = (k >> 3) & 7;
    bt[(size_t)o * KK + tile * 64 + ((ch ^ (o & 7)) << 3) + (k & 7)] = f2bf(v);
  }
}

// ---------- V-build: one wave per dst; pk_fma accumulate; swizzle-baked V store ----------
__global__ __launch_bounds__(256) void k_vbuild(
    const unsigned short* __restrict__ xbf, const float* __restrict__ att,
    const float* __restrict__ deg, const int* __restrict__ rowptr,
    const unsigned* __restrict__ payload, unsigned short* __restrict__ Vb,
    const int c0) {
  __shared__ float attl[RR * NB];                    // 4 KB
  const int t = threadIdx.x;
  *reinterpret_cast<float4*>(&attl[t * 4]) =
      *reinterpret_cast<const float4*>(&att[t * 4]);
  __syncthreads();
  const int lane = t & 63;
  const int n = c0 + blockIdx.x * 4 + (t >> 6);
  if (n >= NN) return;
  const int k0 = rowptr[n], k1 = rowptr[n + 1];

  const int laneBase = (lane >> 4) * 64 + (lane & 1) * 4;  // tile + in-chunk offset
  const unsigned laneCh = (unsigned)((lane >> 1) & 7);

  f32x2 acc2[NB][2];
#pragma unroll
  for (int b = 0; b < NB; ++b) {
    acc2[b][0] = (f32x2){0.f, 0.f};
    acc2[b][1] = (f32x2){0.f, 0.f};
  }

#define XLOAD(PK)                                                            \
  (*reinterpret_cast<const uint2*>(                                          \
      xbf + (size_t)((PK) & 0x3FFFFu) * 256 + laneBase +                     \
      ((laneCh ^ (((PK) & 7u))) << 3)))

  unsigned pkA = 0, pkB = 0;
  uint2 xvA = {0, 0}, xvB = {0, 0};
  if (k0 < k1)     { pkA = payload[k0];     xvA = XLOAD(pkA); }
  if (k0 + 1 < k1) { pkB = payload[k0 + 1]; xvB = XLOAD(pkB); }
  for (int k = k0; k < k1; ++k) {
    unsigned pkC = 0; uint2 xvC = {0, 0};
    if (k + 2 < k1) { pkC = payload[k + 2]; xvC = XLOAD(pkC); }
    const int r = (int)(pkA >> 18);
    const f32x2 x01 = {asf(xvA.x << 16), asf(xvA.x & 0xFFFF0000u)};
    const f32x2 x23 = {asf(xvA.y << 16), asf(xvA.y & 0xFFFF0000u)};
#pragma unroll
    for (int b4 = 0; b4 < 4; ++b4) {
      const float4 a4 = *reinterpret_cast<const float4*>(&attl[r * NB + b4 * 4]);
      const float aa[4] = {a4.x, a4.y, a4.z, a4.w};
#pragma unroll
      for (int q = 0; q < 4; ++q) {
        const int b = b4 * 4 + q;
        acc2[b][0] += aa[q] * x01;                   // v_pk_fma_f32
        acc2[b][1] += aa[q] * x23;
      }
    }
    pkA = pkB; xvA = xvB; pkB = pkC; xvB = xvC;
  }
  const float iv = 1.0f / deg[n];
  const int nl = n - c0;
  unsigned short* vr = Vb + (size_t)nl * 4096 + (lane >> 4) * 64 +
                       ((laneCh ^ (unsigned)(nl & 7)) << 3) + (lane & 1) * 4;
#pragma unroll
  for (int b = 0; b < NB; ++b) {
    ushort4 s;
    s.x = f2bf(acc2[b][0].x * iv); s.y = f2bf(acc2[b][0].y * iv);
    s.z = f2bf(acc2[b][1].x * iv); s.w = f2bf(acc2[b][1].y * iv);
    *reinterpret_cast<ushort4*>(vr + (size_t)b * 256) = s;
  }
}

// ---------- GEMM: out = [V/deg | x] @ bt^T, 128x128 tile, global_load_lds staging ----------
__global__ __launch_bounds__(256) void k_gemm4(
    const unsigned short* __restrict__ Vb, const unsigned short* __restrict__ xbf,
    const unsigned short* __restrict__ bt, float* __restrict__ out, const int c0) {
  __shared__ unsigned short As[2][128 * 64];         // 16 KB each
  __shared__ unsigned short Bs[2][128 * 64];         // 16 KB each
  const int t = threadIdx.x;
  const int rb = blockIdx.x, cb = blockIdx.y;
  const int lane = t & 63, w = t >> 6;
  const int wr = w >> 1, wc = w & 1;                 // 2x2 waves of 64x64
  const int lc = lane & 15, lg = lane >> 4;

  // staging geometry: wave w covers rows/cols [w*32, w*32+32), 4 instrs of 8 rows
  const int lrow8 = lane >> 3;                       // 0..7
  const int lchk  = lane & 7;                        // 0..7
  const int arow0 = rb * 128 + w * 32 + lrow8;       // chunk-local A row (+ i*8)
  const int bcol0 = cb * 128 + w * 32 + lrow8;       // global B col (+ i*8)
  const unsigned short* vrow = Vb  + (size_t)arow0 * 4096 + lchk * 8;
  const unsigned short* xrow = xbf + (size_t)(c0 + arow0) * 256 + lchk * 8;
  const unsigned short* brow = bt  + (size_t)bcol0 * KK + lchk * 8;

#define GL(G, L) __builtin_amdgcn_global_load_lds(                            \
    (const __attribute__((address_space(1))) unsigned int*)(G),               \
    (__attribute__((address_space(3))) unsigned int*)(L), 16, 0, 0)

#define STAGE4(IT, BUF)                                                       \
  {                                                                           \
    const int it_ = (IT);                                                     \
    unsigned short* abase = &As[BUF][w * 2048];                               \
    unsigned short* bbase = &Bs[BUF][w * 2048];                               \
    if (it_ < 64) {                                                           \
      const unsigned short* ga = vrow + it_ * 64;                             \
      _Pragma("unroll")                                                       \
      for (int i = 0; i < 4; ++i) GL(ga + (size_t)i * 8 * 4096, abase + i * 512); \
    } else {                                                                  \
      const unsigned short* ga = xrow + (it_ - 64) * 64;                      \
      _Pragma("unroll")                                                       \
      for (int i = 0; i < 4; ++i) GL(ga + (size_t)i * 8 * 256, abase + i * 512); \
    }                                                                         \
    const unsigned short* gb = brow + it_ * 64;                               \
    _Pragma("unroll")                                                         \
    for (int i = 0; i < 4; ++i) GL(gb + (size_t)i * 8 * KK, bbase + i * 512); \
  }

  f32x4 acc[4][4];
  const f32x4 zf = {0.f, 0.f, 0.f, 0.f};
#pragma unroll
  for (int m = 0; m < 4; ++m)
#pragma unroll
    for (int n = 0; n < 4; ++n) acc[m][n] = zf;

  STAGE4(0, 0);
  asm volatile("s_waitcnt vmcnt(0)" ::: "memory");
  __syncthreads();
  int cur = 0;
  for (int it = 0; it < GITER; ++it) {
    if (it + 1 < GITER) STAGE4(it + 1, cur ^ 1);     // async loads overlap MFMA
#pragma unroll
    for (int kk = 0; kk < 2; ++kk) {
      bf16x8 af[4], bfm[4];
      const int ch = kk * 4 + lg;
#pragma unroll
      for (int m = 0; m < 4; ++m) {
        const int r2 = wr * 64 + m * 16 + lc;
        af[m] = *reinterpret_cast<const bf16x8*>(&As[cur][r2 * 64 + ((ch ^ (r2 & 7)) << 3)]);
      }
#pragma unroll
      for (int n = 0; n < 4; ++n) {
        const int c2 = wc * 64 + n * 16 + lc;
        bfm[n] = *reinterpret_cast<const bf16x8*>(&Bs[cur][c2 * 64 + ((ch ^ (c2 & 7)) << 3)]);
      }
#pragma unroll
      for (int m = 0; m < 4; ++m)
#pragma unroll
        for (int n = 0; n < 4; ++n)
          acc[m][n] = __builtin_amdgcn_mfma_f32_16x16x32_bf16(af[m], bfm[n], acc[m][n], 0, 0, 0);
    }
    asm volatile("s_waitcnt vmcnt(0)" ::: "memory"); // drain stage before barrier
    __syncthreads();
    cur ^= 1;
  }
#pragma unroll
  for (int m = 0; m < 4; ++m) {
#pragma unroll
    for (int j = 0; j < 4; ++j) {
      const int n = c0 + rb * 128 + wr * 64 + m * 16 + lg * 4 + j;
      if (n < NN) {
        float* orow = out + (size_t)n * OUTD + cb * 128 + wc * 64 + lc;
        orow[0]  = acc[m][0][j];
        orow[16] = acc[m][1][j];
        orow[32] = acc[m][2][j];
        orow[48] = acc[m][3][j];
      }
    }
  }
}

extern "C" void kernel_launch(void* const* d_in, const int* in_sizes, int n_in,
                              void* d_out, int out_size, void* d_ws, size_t ws_size,
                              hipStream_t stream) {
  (void)in_sizes; (void)n_in; (void)out_size;
  const float* x     = (const float*)d_in[0];
  const float* att   = (const float*)d_in[1];
  const float* basis = (const float*)d_in[2];
  const float* root  = (const float*)d_in[3];
  const float* deg   = (const float*)d_in[4];
  const int*   esrc  = (const int*)d_in[5];
  const int*   edst  = (const int*)d_in[6];
  float* out = (float*)d_out;

  char* p = (char*)d_ws;
  unsigned short* xbf = (unsigned short*)p; p += (size_t)NN * IND * 2;      // 25.6 MB
  unsigned short* bt  = (unsigned short*)p; p += (size_t)OUTD * KK * 2;     // 2.2 MB
  unsigned* payload   = (unsigned*)p;       p += (size_t)NE * 4;            // 5.1 MB
  int* rowptr         = (int*)p;            p += (size_t)(NN + 1) * 4;
  int* wof            = (int*)p;            p += (size_t)NN * 4;
  int* cnt            = (int*)p;            p += (size_t)NN * 4;
  int* bsum           = (int*)p;            p += 64 * 4;
  int* boff           = (int*)p;            p += 64 * 4;
  uintptr_t up = ((uintptr_t)p + 255) & ~(uintptr_t)255;
  unsigned short* Vb  = (unsigned short*)up;
  const size_t used = (size_t)((char*)Vb - (char*)d_ws);
  const size_t avail = ws_size - used;

  int chunk;
  if      (avail >= (size_t)(NN + 128) * 4096 * 2) chunk = NN;     // 410.7 MB: single pass
  else if (avail >= (size_t)25600 * 4096 * 2)      chunk = 25600;  // 209.7 MB
  else                                             chunk = 12800;

  hipMemsetAsync(cnt, 0, (size_t)NN * 4, stream);
  hipLaunchKernelGGL(k_xbf,     dim3(NN * IND / 2048), dim3(256),  0, stream, x, xbf);
  hipLaunchKernelGGL(k_hist,    dim3(NE / 256),        dim3(256),  0, stream, edst, cnt);
  hipLaunchKernelGGL(k_scan_a,  dim3(SCANB),           dim3(256),  0, stream, cnt, rowptr, bsum);
  hipLaunchKernelGGL(k_scan_b,  dim3(1),               dim3(64),   0, stream, bsum, boff, rowptr);
  hipLaunchKernelGGL(k_scan_c,  dim3(SCANB),           dim3(256),  0, stream, boff, rowptr, wof);
  hipLaunchKernelGGL(k_scatter, dim3(NE / 256),        dim3(256),  0, stream, esrc, edst, wof, payload);
  hipLaunchKernelGGL(k_bt,      dim3(OUTD),            dim3(256),  0, stream, basis, root, bt);

  for (int c0 = 0; c0 < NN; c0 += chunk) {
    const int rows = (NN - c0 < chunk) ? (NN - c0) : chunk;
    hipLaunchKernelGGL(k_vbuild, dim3((rows + 3) / 4), dim3(256), 0, stream,
                       xbf, att, deg, rowptr, payload, Vb, c0);
    hipLaunchKernelGGL(k_gemm4, dim3((rows + 127) / 128, 2), dim3(256), 0, stream,
                       Vb, xbf, bt, out, c0);
  }
}